// Round 1
// baseline (979.828 us; speedup 1.0000x reference)
//
#include <hip/hip_runtime.h>
#include <math.h>

#define NDST 50000
#define NSRC 50000
#define NEDGE 800000
#define DF 128

#define BM 64
#define BN 64
#define BK 16

// ---------------- init: mx = -inf, sm = 0 ----------------
__global__ void init_kernel(float* __restrict__ mx, float* __restrict__ sm, int n) {
    int i = blockIdx.x * blockDim.x + threadIdx.x;
    if (i < n) {
        mx[i] = -INFINITY;
        sm[i] = 0.0f;
    }
}

// float atomic max via sign-split: positive-path int max, negative-path uint min.
// Discriminate on the SIGN BIT so +0.0 -> int-max path, -0.0 -> uint-min path
// (both orderings are then consistent with float max).
__device__ __forceinline__ void atomicMaxF(float* addr, float v) {
    if ((__float_as_uint(v) >> 31) == 0) {
        atomicMax((int*)addr, __float_as_int(v));
    } else {
        atomicMin((unsigned int*)addr, __float_as_uint(v));
    }
}

// ---------------- edge scatter: gather feat_src row, atomic max+sum ----------------
__global__ void edge_kernel(const float* __restrict__ feat_src,
                            const int* __restrict__ src_idx,
                            const int* __restrict__ dst_idx,
                            float* __restrict__ mx, float* __restrict__ sm) {
    unsigned int gid = blockIdx.x * 256u + threadIdx.x;
    unsigned int e = gid >> 7;
    unsigned int f = gid & 127u;
    if (e >= NEDGE) return;
    int s = src_idx[e];
    int d = dst_idx[e];
    float v = feat_src[s * DF + f];
    atomicAdd(&sm[d * DF + f], v);
    atomicMaxF(&mx[d * DF + f], v);
}

// ---------------- weight prep (transpose to [K][N] layouts) ----------------
// Wz_t[k][c], k<128: W2[c,k] + W2[c,128+k]   (mx appears twice in concat)
//             k>=128: W2[c,256+(k-128)]      (sm part)
__global__ void prep_wz(const float* __restrict__ W2, float* __restrict__ Wz_t) {
    int i = blockIdx.x * 256 + threadIdx.x;
    if (i >= 256 * 128) return;
    int k = i >> 7;
    int c = i & 127;
    float v;
    if (k < 128) v = W2[c * 384 + k] + W2[c * 384 + 128 + k];
    else         v = W2[c * 384 + 256 + (k - 128)];
    Wz_t[k * 128 + c] = v;
}

__global__ void prep_w1(const float* __restrict__ W1, float* __restrict__ W1_t) {
    int i = blockIdx.x * 256 + threadIdx.x;
    if (i >= 128 * 128) return;
    int k = i >> 7;
    int c = i & 127;
    W1_t[k * 128 + c] = W1[c * 128 + k];
}

__global__ void prep_w3(const float* __restrict__ W3, float* __restrict__ W3_t) {
    int i = blockIdx.x * 256 + threadIdx.x;
    if (i >= 256 * 128) return;
    int k = i >> 7;   // 0..255
    int c = i & 127;
    W3_t[k * 128 + c] = W3[c * 256 + k];
}

// ---------------- fused GEMM + bias + relu ----------------
// C[m, coloff + n] = relu( sum_k A[m,k] * Wt[k][n] + bias[n] ),  n in [0,128)
// A is split into up to two [*,128] column-parts (a0: k<128, a1: k>=128),
// each with its own row stride. fix0: replace -inf with 0 in part 0 (mx fix).
__global__ __launch_bounds__(256)
void gemm_bias_relu(const float* __restrict__ a0, int a0s,
                    const float* __restrict__ a1, int a1s,
                    int fix0,
                    const float* __restrict__ Wt,
                    const float* __restrict__ bias,
                    float* __restrict__ C, int ldc, int coloff,
                    int M, int K) {
    __shared__ float As[BK][BM + 4];   // [k][m], +4 pad keeps float4 alignment
    __shared__ float Bs[BK][BN];       // [k][n]
    int tid = threadIdx.x;
    int bm = blockIdx.x * BM;
    int bn = blockIdx.y * BN;
    int tx = tid & 15;
    int ty = tid >> 4;
    float acc[4][4] = {{0.f}};

    int ar = tid >> 2;            // 0..63 : row within A tile
    int ak = (tid & 3) * 4;       // 0,4,8,12 : k within A tile (float4)
    int wk = tid >> 4;            // 0..15 : k row of W tile
    int wn = (tid & 15) * 4;      // col within W tile (float4)

    for (int k0 = 0; k0 < K; k0 += BK) {
        int part = k0 >> 7;                    // BK divides 128 -> uniform per tile
        const float* ap = part ? a1 : a0;
        int as = part ? a1s : a0s;
        int kl = (k0 & 127) + ak;
        int m = bm + ar;
        float4 av = make_float4(0.f, 0.f, 0.f, 0.f);
        if (m < M) av = *(const float4*)(ap + (size_t)m * as + kl);
        if (fix0 && part == 0) {               // zero-degree dst: -inf -> 0
            av.x = (av.x == -INFINITY) ? 0.f : av.x;
            av.y = (av.y == -INFINITY) ? 0.f : av.y;
            av.z = (av.z == -INFINITY) ? 0.f : av.z;
            av.w = (av.w == -INFINITY) ? 0.f : av.w;
        }
        As[ak + 0][ar] = av.x;
        As[ak + 1][ar] = av.y;
        As[ak + 2][ar] = av.z;
        As[ak + 3][ar] = av.w;

        float4 wv = *(const float4*)(Wt + (size_t)(k0 + wk) * 128 + bn + wn);
        *(float4*)&Bs[wk][wn] = wv;
        __syncthreads();

        #pragma unroll
        for (int kk = 0; kk < BK; ++kk) {
            float4 a4 = *(const float4*)&As[kk][ty * 4];
            float4 b4 = *(const float4*)&Bs[kk][tx * 4];
            float a[4] = {a4.x, a4.y, a4.z, a4.w};
            float b[4] = {b4.x, b4.y, b4.z, b4.w};
            #pragma unroll
            for (int i = 0; i < 4; ++i)
                #pragma unroll
                for (int j = 0; j < 4; ++j)
                    acc[i][j] = fmaf(a[i], b[j], acc[i][j]);
        }
        __syncthreads();
    }

    #pragma unroll
    for (int i = 0; i < 4; ++i) {
        int m = bm + ty * 4 + i;
        if (m >= M) continue;
        #pragma unroll
        for (int j = 0; j < 4; ++j) {
            int n = bn + tx * 4 + j;
            float v = acc[i][j] + bias[n];
            v = fmaxf(v, 0.0f);
            C[(size_t)m * ldc + coloff + n] = v;
        }
    }
}

extern "C" void kernel_launch(void* const* d_in, const int* in_sizes, int n_in,
                              void* d_out, int out_size, void* d_ws, size_t ws_size,
                              hipStream_t stream) {
    const float* feat_src = (const float*)d_in[0];
    const float* feat_dst = (const float*)d_in[1];
    const float* W1 = (const float*)d_in[2];
    const float* b1 = (const float*)d_in[3];
    const float* W2 = (const float*)d_in[4];
    const float* b2 = (const float*)d_in[5];
    const float* W3 = (const float*)d_in[6];
    const float* b3 = (const float*)d_in[7];
    const int* src_idx = (const int*)d_in[8];
    const int* dst_idx = (const int*)d_in[9];

    float* out = (float*)d_out;
    // mx aliases d_out (exactly NDST*128 floats). It is consumed by GEMM1 and
    // d_out is only (re)written by GEMM3, which runs strictly after on `stream`.
    float* mx = out;

    float* sm   = (float*)d_ws;                    // NDST*128
    float* h    = sm + (size_t)NDST * DF;          // NDST*256 (relu'd [z2|z1])
    float* Wz_t = h + (size_t)NDST * 256;          // 256*128
    float* W1_t = Wz_t + 256 * 128;                // 128*128
    float* W3_t = W1_t + 128 * 128;                // 256*128

    int n_init = NDST * DF;
    init_kernel<<<(n_init + 255) / 256, 256, 0, stream>>>(mx, sm, n_init);

    edge_kernel<<<(NEDGE * DF) / 256, 256, 0, stream>>>(feat_src, src_idx, dst_idx, mx, sm);

    prep_wz<<<(256 * 128 + 255) / 256, 256, 0, stream>>>(W2, Wz_t);
    prep_w1<<<(128 * 128 + 255) / 256, 256, 0, stream>>>(W1, W1_t);
    prep_w3<<<(256 * 128 + 255) / 256, 256, 0, stream>>>(W3, W3_t);

    dim3 gemm_grid((NDST + BM - 1) / BM, 128 / BN);
    // z2 = [mx|sm] @ Wz_t + b2, relu -> h[:, 0:128]
    gemm_bias_relu<<<gemm_grid, 256, 0, stream>>>(mx, DF, sm, DF, 1,
                                                  Wz_t, b2, h, 256, 0, NDST, 256);
    // z1 = feat_dst @ W1_t + b1, relu -> h[:, 128:256]
    gemm_bias_relu<<<gemm_grid, 256, 0, stream>>>(feat_dst, DF, nullptr, 0, 0,
                                                  W1_t, b1, h, 256, 128, NDST, 128);
    // out = relu(h @ W3_t + b3)
    gemm_bias_relu<<<gemm_grid, 256, 0, stream>>>(h, 256, h + 128, 256, 0,
                                                  W3_t, b3, out, DF, 0, NDST, 256);
}

// Round 2
// 436.267 us; speedup vs baseline: 2.2459x; 2.2459x over previous
//
#include <hip/hip_runtime.h>
#include <math.h>

#define NDST 50000
#define NSRC 50000
#define NEDGE 800000
#define DF 128

#define BM 64
#define BN 64
#define BK 16

// ---------------- CSR build ----------------
__global__ void zero_cnt(int* __restrict__ cnt) {
    int i = blockIdx.x * 256 + threadIdx.x;
    if (i < NDST) cnt[i] = 0;
}

__global__ void count_deg(const int* __restrict__ dst_idx, int* __restrict__ cnt) {
    int e = blockIdx.x * 256 + threadIdx.x;
    if (e < NEDGE) atomicAdd(&cnt[dst_idx[e]], 1);
}

// single-block exclusive scan of 50k counts -> offs[0..NDST], cursor copy
__global__ __launch_bounds__(1024)
void scan_kernel(const int* __restrict__ cnt, int* __restrict__ offs,
                 int* __restrict__ cursor) {
    __shared__ int part[1024];
    int t = threadIdx.x;
    const int CH = (NDST + 1023) / 1024;   // 49
    int lo = t * CH;
    int hi = min(NDST, lo + CH);
    int s = 0;
    for (int i = lo; i < hi; ++i) s += cnt[i];
    part[t] = s;
    __syncthreads();
    // Hillis-Steele inclusive scan (read-all / barrier / write-all)
    for (int off = 1; off < 1024; off <<= 1) {
        int v = (t >= off) ? part[t - off] : 0;
        __syncthreads();
        part[t] += v;
        __syncthreads();
    }
    int run = (t == 0) ? 0 : part[t - 1];
    for (int i = lo; i < hi; ++i) {
        offs[i] = run;
        cursor[i] = run;
        run += cnt[i];
    }
    if (t == 1023) offs[NDST] = part[1023];
}

__global__ void scatter_edges(const int* __restrict__ src_idx,
                              const int* __restrict__ dst_idx,
                              int* __restrict__ cursor, int* __restrict__ esrc) {
    int e = blockIdx.x * 256 + threadIdx.x;
    if (e < NEDGE) {
        int d = dst_idx[e];
        int pos = atomicAdd(&cursor[d], 1);
        esrc[pos] = src_idx[e];
    }
}

// ---------------- aggregate: per-dst register max+sum ----------------
// 128 threads per dst node (2 nodes / 256-block); thread f owns feature f.
__global__ __launch_bounds__(256)
void aggregate(const float* __restrict__ feat_src, const int* __restrict__ esrc,
               const int* __restrict__ offs,
               float* __restrict__ mx, float* __restrict__ sm) {
    int nid = blockIdx.x * 2 + (threadIdx.x >> 7);
    int f = threadIdx.x & 127;
    if (nid >= NDST) return;
    int e0 = offs[nid];
    int e1 = offs[nid + 1];
    float mxv = -INFINITY, smv = 0.f;
    if (e0 < e1) {
        int s = esrc[e0];
        for (int e = e0 + 1; e < e1; ++e) {
            int sn = esrc[e];                       // prefetch next index
            float v = feat_src[(size_t)s * DF + f];
            mxv = fmaxf(mxv, v);
            smv += v;
            s = sn;
        }
        float v = feat_src[(size_t)s * DF + f];
        mxv = fmaxf(mxv, v);
        smv += v;
    } else {
        mxv = 0.f;   // zero-degree dst: DGL convention (-inf -> 0)
    }
    mx[(size_t)nid * DF + f] = mxv;
    sm[(size_t)nid * DF + f] = smv;
}

// ---------------- weight prep (transpose to [K][N] layouts) ----------------
__global__ void prep_wz(const float* __restrict__ W2, float* __restrict__ Wz_t) {
    int i = blockIdx.x * 256 + threadIdx.x;
    if (i >= 256 * 128) return;
    int k = i >> 7;
    int c = i & 127;
    float v;
    if (k < 128) v = W2[c * 384 + k] + W2[c * 384 + 128 + k];
    else         v = W2[c * 384 + 256 + (k - 128)];
    Wz_t[k * 128 + c] = v;
}

__global__ void prep_w1(const float* __restrict__ W1, float* __restrict__ W1_t) {
    int i = blockIdx.x * 256 + threadIdx.x;
    if (i >= 128 * 128) return;
    int k = i >> 7;
    int c = i & 127;
    W1_t[k * 128 + c] = W1[c * 128 + k];
}

__global__ void prep_w3(const float* __restrict__ W3, float* __restrict__ W3_t) {
    int i = blockIdx.x * 256 + threadIdx.x;
    if (i >= 256 * 128) return;
    int k = i >> 7;   // 0..255
    int c = i & 127;
    W3_t[k * 128 + c] = W3[c * 256 + k];
}

// ---------------- fused GEMM + bias + relu ----------------
// C[m, coloff + n] = relu( sum_k A[m,k] * Wt[k][n] + bias[n] ),  n in [0,128)
// A split into up to two [*,128] column-parts (a0: k<128, a1: k>=128).
__global__ __launch_bounds__(256)
void gemm_bias_relu(const float* __restrict__ a0, int a0s,
                    const float* __restrict__ a1, int a1s,
                    const float* __restrict__ Wt,
                    const float* __restrict__ bias,
                    float* __restrict__ C, int ldc, int coloff,
                    int M, int K) {
    __shared__ float As[BK][BM + 4];
    __shared__ float Bs[BK][BN];
    int tid = threadIdx.x;
    int bm = blockIdx.x * BM;
    int bn = blockIdx.y * BN;
    int tx = tid & 15;
    int ty = tid >> 4;
    float acc[4][4] = {{0.f}};

    int ar = tid >> 2;
    int ak = (tid & 3) * 4;
    int wk = tid >> 4;
    int wn = (tid & 15) * 4;

    for (int k0 = 0; k0 < K; k0 += BK) {
        int part = k0 >> 7;
        const float* ap = part ? a1 : a0;
        int as = part ? a1s : a0s;
        int kl = (k0 & 127) + ak;
        int m = bm + ar;
        float4 av = make_float4(0.f, 0.f, 0.f, 0.f);
        if (m < M) av = *(const float4*)(ap + (size_t)m * as + kl);
        As[ak + 0][ar] = av.x;
        As[ak + 1][ar] = av.y;
        As[ak + 2][ar] = av.z;
        As[ak + 3][ar] = av.w;

        float4 wv = *(const float4*)(Wt + (size_t)(k0 + wk) * 128 + bn + wn);
        *(float4*)&Bs[wk][wn] = wv;
        __syncthreads();

        #pragma unroll
        for (int kk = 0; kk < BK; ++kk) {
            float4 a4 = *(const float4*)&As[kk][ty * 4];
            float4 b4 = *(const float4*)&Bs[kk][tx * 4];
            float a[4] = {a4.x, a4.y, a4.z, a4.w};
            float b[4] = {b4.x, b4.y, b4.z, b4.w};
            #pragma unroll
            for (int i = 0; i < 4; ++i)
                #pragma unroll
                for (int j = 0; j < 4; ++j)
                    acc[i][j] = fmaf(a[i], b[j], acc[i][j]);
        }
        __syncthreads();
    }

    #pragma unroll
    for (int i = 0; i < 4; ++i) {
        int m = bm + ty * 4 + i;
        if (m >= M) continue;
        #pragma unroll
        for (int j = 0; j < 4; ++j) {
            int n = bn + tx * 4 + j;
            float v = acc[i][j] + bias[n];
            v = fmaxf(v, 0.0f);
            C[(size_t)m * ldc + coloff + n] = v;
        }
    }
}

extern "C" void kernel_launch(void* const* d_in, const int* in_sizes, int n_in,
                              void* d_out, int out_size, void* d_ws, size_t ws_size,
                              hipStream_t stream) {
    const float* feat_src = (const float*)d_in[0];
    const float* feat_dst = (const float*)d_in[1];
    const float* W1 = (const float*)d_in[2];
    const float* b1 = (const float*)d_in[3];
    const float* W2 = (const float*)d_in[4];
    const float* b2 = (const float*)d_in[5];
    const float* W3 = (const float*)d_in[6];
    const float* b3 = (const float*)d_in[7];
    const int* src_idx = (const int*)d_in[8];
    const int* dst_idx = (const int*)d_in[9];

    float* out = (float*)d_out;
    float* mx = out;   // aliases d_out; consumed by GEMM1, overwritten by GEMM3 last

    float* sm   = (float*)d_ws;                    // NDST*128 f
    float* h    = sm + (size_t)NDST * DF;          // NDST*256 f
    float* Wz_t = h + (size_t)NDST * 256;          // 256*128 f
    float* W1_t = Wz_t + 256 * 128;                // 128*128 f
    float* W3_t = W1_t + 128 * 128;                // 256*128 f
    int* cnt    = (int*)(W3_t + 256 * 128);        // NDST
    int* offs   = cnt + NDST;                      // NDST+1
    int* cursor = offs + NDST + 1;                 // NDST
    int* esrc   = cursor + NDST;                   // NEDGE

    // CSR build
    zero_cnt<<<(NDST + 255) / 256, 256, 0, stream>>>(cnt);
    count_deg<<<(NEDGE + 255) / 256, 256, 0, stream>>>(dst_idx, cnt);
    scan_kernel<<<1, 1024, 0, stream>>>(cnt, offs, cursor);
    scatter_edges<<<(NEDGE + 255) / 256, 256, 0, stream>>>(src_idx, dst_idx, cursor, esrc);

    // weight prep (independent of CSR)
    prep_wz<<<(256 * 128 + 255) / 256, 256, 0, stream>>>(W2, Wz_t);
    prep_w1<<<(128 * 128 + 255) / 256, 256, 0, stream>>>(W1, W1_t);
    prep_w3<<<(256 * 128 + 255) / 256, 256, 0, stream>>>(W3, W3_t);

    // aggregation: register max+sum per dst
    aggregate<<<(NDST + 1) / 2, 256, 0, stream>>>(feat_src, esrc, offs, mx, sm);

    dim3 gemm_grid((NDST + BM - 1) / BM, 128 / BN);
    // z2 = [mx|sm] @ Wz_t + b2, relu -> h[:, 0:128]
    gemm_bias_relu<<<gemm_grid, 256, 0, stream>>>(mx, DF, sm, DF,
                                                  Wz_t, b2, h, 256, 0, NDST, 256);
    // z1 = feat_dst @ W1_t + b1, relu -> h[:, 128:256]
    gemm_bias_relu<<<gemm_grid, 256, 0, stream>>>(feat_dst, DF, nullptr, 0,
                                                  W1_t, b1, h, 256, 128, NDST, 128);
    // out = relu(h @ W3_t + b3)
    gemm_bias_relu<<<gemm_grid, 256, 0, stream>>>(h, 256, h + 128, 256,
                                                  W3_t, b3, out, DF, 0, NDST, 256);
}

// Round 3
// 261.830 us; speedup vs baseline: 3.7422x; 1.6662x over previous
//
#include <hip/hip_runtime.h>
#include <math.h>

#define NDST 50000
#define NSRC 50000
#define NEDGE 800000
#define DF 128

typedef __attribute__((ext_vector_type(4))) float f32x4;
typedef __attribute__((ext_vector_type(8))) short bf16x8;

__device__ __forceinline__ ushort f2bf(float f) {
    union { float f; unsigned int u; } c; c.f = f;
    unsigned int u = c.u;
    unsigned int r = (u + 0x7fffu + ((u >> 16) & 1u)) >> 16;   // RNE
    return (ushort)r;
}

// ---------------- CSR build ----------------
__global__ void zero_cnt(int* __restrict__ cnt) {
    int i = blockIdx.x * 256 + threadIdx.x;
    if (i < NDST) cnt[i] = 0;
}

__global__ void count_deg(const int* __restrict__ dst_idx, int* __restrict__ cnt) {
    int e = blockIdx.x * 256 + threadIdx.x;
    if (e < NEDGE) atomicAdd(&cnt[dst_idx[e]], 1);
}

// phase1: per-256-chunk sums (196 blocks)
__global__ void scan_phase1(const int* __restrict__ cnt, int* __restrict__ bsum) {
    __shared__ int ws[4];
    int b = blockIdx.x, t = threadIdx.x;
    int i = b * 256 + t;
    int v = (i < NDST) ? cnt[i] : 0;
    #pragma unroll
    for (int off = 32; off > 0; off >>= 1) v += __shfl_down(v, off, 64);
    if ((t & 63) == 0) ws[t >> 6] = v;
    __syncthreads();
    if (t == 0) bsum[b] = ws[0] + ws[1] + ws[2] + ws[3];
}

// phase2: exclusive scan of nb (<=256) block sums, single block
__global__ void scan_phase2(const int* __restrict__ bsum, int* __restrict__ bpre, int nb) {
    __shared__ int s[256];
    int t = threadIdx.x;
    int v = (t < nb) ? bsum[t] : 0;
    s[t] = v;
    __syncthreads();
    for (int off = 1; off < 256; off <<= 1) {
        int u = (t >= off) ? s[t - off] : 0;
        __syncthreads();
        s[t] += u;
        __syncthreads();
    }
    bpre[t] = (t == 0) ? 0 : s[t - 1];
}

// phase3: local exclusive scan + block prefix -> offs, cursor
__global__ void scan_phase3(const int* __restrict__ cnt, const int* __restrict__ bpre,
                            int* __restrict__ offs, int* __restrict__ cursor) {
    __shared__ int s[256];
    int b = blockIdx.x, t = threadIdx.x;
    int i = b * 256 + t;
    int v = (i < NDST) ? cnt[i] : 0;
    s[t] = v;
    __syncthreads();
    for (int off = 1; off < 256; off <<= 1) {
        int u = (t >= off) ? s[t - off] : 0;
        __syncthreads();
        s[t] += u;
        __syncthreads();
    }
    if (i < NDST) {
        int excl = bpre[b] + s[t] - v;
        offs[i] = excl;
        cursor[i] = excl;
        if (i == NDST - 1) offs[NDST] = excl + v;
    }
}

__global__ void scatter_edges(const int* __restrict__ src_idx,
                              const int* __restrict__ dst_idx,
                              int* __restrict__ cursor, int* __restrict__ esrc) {
    int e = blockIdx.x * 256 + threadIdx.x;
    if (e < NEDGE) {
        int d = dst_idx[e];
        int pos = atomicAdd(&cursor[d], 1);
        esrc[pos] = src_idx[e];
    }
}

// ---------------- aggregate: per-dst register max+sum ----------------
__global__ __launch_bounds__(256)
void aggregate(const float* __restrict__ feat_src, const int* __restrict__ esrc,
               const int* __restrict__ offs,
               float* __restrict__ mx, float* __restrict__ sm) {
    int nid = blockIdx.x * 2 + (threadIdx.x >> 7);
    int f = threadIdx.x & 127;
    if (nid >= NDST) return;
    int e0 = offs[nid];
    int e1 = offs[nid + 1];
    float mxv = -INFINITY, smv = 0.f;
    if (e0 < e1) {
        int s = esrc[e0];
        for (int e = e0 + 1; e < e1; ++e) {
            int sn = esrc[e];
            float v = feat_src[(size_t)s * DF + f];
            mxv = fmaxf(mxv, v);
            smv += v;
            s = sn;
        }
        float v = feat_src[(size_t)s * DF + f];
        mxv = fmaxf(mxv, v);
        smv += v;
    } else {
        mxv = 0.f;   // zero-degree dst: -inf -> 0
    }
    mx[(size_t)nid * DF + f] = mxv;
    sm[(size_t)nid * DF + f] = smv;
}

// ---------------- weight prep: f32 -> bf16, [c][k] layout (no transpose) ----------------
__global__ void prep_wz(const float* __restrict__ W2, ushort* __restrict__ Wz_b) {
    int i = blockIdx.x * 256 + threadIdx.x;
    if (i >= 128 * 256) return;
    int c = i >> 8, k = i & 255;
    float v = (k < 128) ? (W2[c * 384 + k] + W2[c * 384 + 128 + k])
                        : W2[c * 384 + 128 + k];
    Wz_b[c * 256 + k] = f2bf(v);
}

__global__ void prep_w1(const float* __restrict__ W1, ushort* __restrict__ W1_b) {
    int i = blockIdx.x * 256 + threadIdx.x;
    if (i >= 128 * 128) return;
    W1_b[i] = f2bf(W1[i]);
}

__global__ void prep_w3(const float* __restrict__ W3, ushort* __restrict__ W3_b) {
    int i = blockIdx.x * 256 + threadIdx.x;
    if (i >= 128 * 256) return;
    W3_b[i] = f2bf(W3[i]);
}

// ---------------- MFMA bf16 GEMM + bias + relu ----------------
// C[m, coloff+n] = relu(sum_k A[m,k] * W[n,k] + bias[n]), n in [0,128)
// A: f32, split in two 128-col parts (a0: k<128, a1: k>=128), converted to
// bf16 during LDS staging. W: pre-converted bf16 [128][K] row-major.
#define GBM 128
#define GBK 32
#define LDW 40   // padded LDS row (32 used + 8), 80B stride -> 2-way conflicts only

__global__ __launch_bounds__(256)
void gemm_mfma(const float* __restrict__ a0, int a0s,
               const float* __restrict__ a1, int a1s,
               const ushort* __restrict__ Wb,
               const float* __restrict__ bias,
               float* __restrict__ C, int ldc, int coloff,
               int M, int K) {
    __shared__ ushort As[GBM * LDW];
    __shared__ ushort Ws[128 * LDW];
    int tid = threadIdx.x;
    int bm = blockIdx.x * GBM;
    int wid = tid >> 6, lane = tid & 63;
    int wm = (wid & 1) * 64, wn = (wid >> 1) * 64;     // 2x2 wave grid
    int lrow = lane & 15, lk8 = (lane >> 4) * 8;       // fragment addressing

    f32x4 acc[4][4];
    #pragma unroll
    for (int i = 0; i < 4; ++i)
        #pragma unroll
        for (int j = 0; j < 4; ++j)
            acc[i][j] = (f32x4){0.f, 0.f, 0.f, 0.f};

    int sr = tid >> 1;            // staged row 0..127
    int skh = (tid & 1) * 16;     // k-half (16 elems)

    for (int k0 = 0; k0 < K; k0 += GBK) {
        // ---- stage A (f32 -> bf16) ----
        int part = k0 >> 7;
        const float* ap = part ? a1 : a0;
        int as = part ? a1s : a0s;
        int m = bm + sr;
        unsigned int pk[8];
        if (m < M) {
            const float* p = ap + (size_t)m * as + (k0 & 127) + skh;
            #pragma unroll
            for (int j = 0; j < 8; ++j) {
                float x = p[2 * j], y = p[2 * j + 1];
                pk[j] = (unsigned int)f2bf(x) | ((unsigned int)f2bf(y) << 16);
            }
        } else {
            #pragma unroll
            for (int j = 0; j < 8; ++j) pk[j] = 0;
        }
        uint4 w0 = make_uint4(pk[0], pk[1], pk[2], pk[3]);
        uint4 w1 = make_uint4(pk[4], pk[5], pk[6], pk[7]);
        *(uint4*)&As[sr * LDW + skh] = w0;
        *(uint4*)&As[sr * LDW + skh + 8] = w1;

        // ---- stage W (bf16 direct) ----
        const ushort* wp = Wb + (size_t)sr * K + k0 + skh;
        uint4 v0 = *(const uint4*)wp;
        uint4 v1 = *(const uint4*)(wp + 8);
        *(uint4*)&Ws[sr * LDW + skh] = v0;
        *(uint4*)&Ws[sr * LDW + skh + 8] = v1;
        __syncthreads();

        // ---- fragments + MFMA ----
        bf16x8 af[4], bfr[4];
        #pragma unroll
        for (int mi = 0; mi < 4; ++mi)
            af[mi] = *(const bf16x8*)&As[(wm + mi * 16 + lrow) * LDW + lk8];
        #pragma unroll
        for (int ni = 0; ni < 4; ++ni)
            bfr[ni] = *(const bf16x8*)&Ws[(wn + ni * 16 + lrow) * LDW + lk8];
        #pragma unroll
        for (int mi = 0; mi < 4; ++mi)
            #pragma unroll
            for (int ni = 0; ni < 4; ++ni)
                acc[mi][ni] = __builtin_amdgcn_mfma_f32_16x16x32_bf16(
                    af[mi], bfr[ni], acc[mi][ni], 0, 0, 0);
        __syncthreads();
    }

    // ---- epilogue: bias + relu, C/D layout col=lane&15, row=(lane>>4)*4+r ----
    int rbase = (lane >> 4) * 4;
    #pragma unroll
    for (int ni = 0; ni < 4; ++ni) {
        int n = wn + ni * 16 + lrow;
        float bv = bias[n];
        #pragma unroll
        for (int mi = 0; mi < 4; ++mi) {
            #pragma unroll
            for (int r = 0; r < 4; ++r) {
                int m = bm + wm + mi * 16 + rbase + r;
                if (m < M) {
                    float v = acc[mi][ni][r] + bv;
                    C[(size_t)m * ldc + coloff + n] = fmaxf(v, 0.f);
                }
            }
        }
    }
}

extern "C" void kernel_launch(void* const* d_in, const int* in_sizes, int n_in,
                              void* d_out, int out_size, void* d_ws, size_t ws_size,
                              hipStream_t stream) {
    const float* feat_src = (const float*)d_in[0];
    const float* feat_dst = (const float*)d_in[1];
    const float* W1 = (const float*)d_in[2];
    const float* b1 = (const float*)d_in[3];
    const float* W2 = (const float*)d_in[4];
    const float* b2 = (const float*)d_in[5];
    const float* W3 = (const float*)d_in[6];
    const float* b3 = (const float*)d_in[7];
    const int* src_idx = (const int*)d_in[8];
    const int* dst_idx = (const int*)d_in[9];

    float* out = (float*)d_out;
    float* mx = out;   // aliases d_out; consumed by GEMM1, overwritten last by GEMM3

    float* sm    = (float*)d_ws;                       // NDST*128 f
    float* h     = sm + (size_t)NDST * DF;             // NDST*256 f
    ushort* Wz_b = (ushort*)(h + (size_t)NDST * 256);  // 128*256
    ushort* W1_b = Wz_b + 128 * 256;                   // 128*128
    ushort* W3_b = W1_b + 128 * 128;                   // 128*256
    int* cnt     = (int*)(W3_b + 128 * 256);           // NDST
    int* offs    = cnt + NDST;                         // NDST+1
    int* cursor  = offs + NDST + 1;                    // NDST
    int* esrc    = cursor + NDST;                      // NEDGE
    int* bsum    = esrc + NEDGE;                       // 196
    int* bpre    = bsum + 256;                         // 256

    const int NB = (NDST + 255) / 256;   // 196

    // CSR build
    zero_cnt<<<NB, 256, 0, stream>>>(cnt);
    count_deg<<<(NEDGE + 255) / 256, 256, 0, stream>>>(dst_idx, cnt);
    scan_phase1<<<NB, 256, 0, stream>>>(cnt, bsum);
    scan_phase2<<<1, 256, 0, stream>>>(bsum, bpre, NB);
    scan_phase3<<<NB, 256, 0, stream>>>(cnt, bpre, offs, cursor);
    scatter_edges<<<(NEDGE + 255) / 256, 256, 0, stream>>>(src_idx, dst_idx, cursor, esrc);

    // weight prep
    prep_wz<<<(128 * 256 + 255) / 256, 256, 0, stream>>>(W2, Wz_b);
    prep_w1<<<(128 * 128 + 255) / 256, 256, 0, stream>>>(W1, W1_b);
    prep_w3<<<(128 * 256 + 255) / 256, 256, 0, stream>>>(W3, W3_b);

    // aggregation
    aggregate<<<(NDST + 1) / 2, 256, 0, stream>>>(feat_src, esrc, offs, mx, sm);

    dim3 ggrid((NDST + GBM - 1) / GBM, 1);
    // z2 = [mx|sm] @ Wz^T + b2, relu -> h[:, 0:128]
    gemm_mfma<<<ggrid, 256, 0, stream>>>(mx, DF, sm, DF, Wz_b, b2, h, 256, 0, NDST, 256);
    // z1 = feat_dst @ W1^T + b1, relu -> h[:, 128:256]
    gemm_mfma<<<ggrid, 256, 0, stream>>>(feat_dst, DF, nullptr, 0, W1_b, b1, h, 256, 128, NDST, 128);
    // out = relu(h @ W3^T + b3)
    gemm_mfma<<<ggrid, 256, 0, stream>>>(h, 256, h + 128, 256, W3_b, b3, out, DF, 0, NDST, 256);
}

// Round 4
// 206.212 us; speedup vs baseline: 4.7516x; 1.2697x over previous
//
#include <hip/hip_runtime.h>
#include <math.h>

#define NDST 50000
#define NSRC 50000
#define NEDGE 800000
#define DF 128

typedef __attribute__((ext_vector_type(4))) float f32x4;
typedef __attribute__((ext_vector_type(8))) short bf16x8;

__device__ __forceinline__ ushort f2bf(float f) {
    union { float f; unsigned int u; } c; c.f = f;
    unsigned int u = c.u;
    unsigned int r = (u + 0x7fffu + ((u >> 16) & 1u)) >> 16;   // RNE
    return (ushort)r;
}
__device__ __forceinline__ float bflo(unsigned int u) {
    union { unsigned int u; float f; } c; c.u = u << 16; return c.f;
}
__device__ __forceinline__ float bfhi(unsigned int u) {
    union { unsigned int u; float f; } c; c.u = u & 0xffff0000u; return c.f;
}

// ---------------- CSR build ----------------
__global__ void zero_cnt(int* __restrict__ cnt) {
    int i = blockIdx.x * 256 + threadIdx.x;
    if (i < NDST) cnt[i] = 0;
}

__global__ void count_deg(const int* __restrict__ dst_idx, int* __restrict__ cnt) {
    int e = blockIdx.x * 256 + threadIdx.x;
    if (e < NEDGE) atomicAdd(&cnt[dst_idx[e]], 1);
}

__global__ void scan_phase1(const int* __restrict__ cnt, int* __restrict__ bsum) {
    __shared__ int ws[4];
    int b = blockIdx.x, t = threadIdx.x;
    int i = b * 256 + t;
    int v = (i < NDST) ? cnt[i] : 0;
    #pragma unroll
    for (int off = 32; off > 0; off >>= 1) v += __shfl_down(v, off, 64);
    if ((t & 63) == 0) ws[t >> 6] = v;
    __syncthreads();
    if (t == 0) bsum[b] = ws[0] + ws[1] + ws[2] + ws[3];
}

__global__ void scan_phase2(const int* __restrict__ bsum, int* __restrict__ bpre, int nb) {
    __shared__ int s[256];
    int t = threadIdx.x;
    int v = (t < nb) ? bsum[t] : 0;
    s[t] = v;
    __syncthreads();
    for (int off = 1; off < 256; off <<= 1) {
        int u = (t >= off) ? s[t - off] : 0;
        __syncthreads();
        s[t] += u;
        __syncthreads();
    }
    bpre[t] = (t == 0) ? 0 : s[t - 1];
}

__global__ void scan_phase3(const int* __restrict__ cnt, const int* __restrict__ bpre,
                            int* __restrict__ offs, int* __restrict__ cursor) {
    __shared__ int s[256];
    int b = blockIdx.x, t = threadIdx.x;
    int i = b * 256 + t;
    int v = (i < NDST) ? cnt[i] : 0;
    s[t] = v;
    __syncthreads();
    for (int off = 1; off < 256; off <<= 1) {
        int u = (t >= off) ? s[t - off] : 0;
        __syncthreads();
        s[t] += u;
        __syncthreads();
    }
    if (i < NDST) {
        int excl = bpre[b] + s[t] - v;
        offs[i] = excl;
        cursor[i] = excl;
        if (i == NDST - 1) offs[NDST] = excl + v;
    }
}

__global__ void scatter_edges(const int* __restrict__ src_idx,
                              const int* __restrict__ dst_idx,
                              int* __restrict__ cursor, int* __restrict__ esrc) {
    int e = blockIdx.x * 256 + threadIdx.x;
    if (e < NEDGE) {
        int d = dst_idx[e];
        int pos = atomicAdd(&cursor[d], 1);
        esrc[pos] = src_idx[e];
    }
}

// ---------------- feat_src -> bf16 ----------------
__global__ void conv_fs(const float* __restrict__ fs, unsigned int* __restrict__ fs_b) {
    int i = blockIdx.x * 256 + threadIdx.x;   // each handles 4 floats -> 2 uints
    if (i >= NSRC * DF / 4) return;
    float4 v = *(const float4*)(fs + (size_t)i * 4);
    unsigned int lo = (unsigned int)f2bf(v.x) | ((unsigned int)f2bf(v.y) << 16);
    unsigned int hi = (unsigned int)f2bf(v.z) | ((unsigned int)f2bf(v.w) << 16);
    *(uint2*)(fs_b + (size_t)i * 2) = make_uint2(lo, hi);
}

// ---------------- weight prep (fused): f32 -> bf16, [c][k] ----------------
__global__ void prep_weights(const float* __restrict__ W2, const float* __restrict__ W1,
                             const float* __restrict__ W3,
                             ushort* __restrict__ Wz_b, ushort* __restrict__ W1_b,
                             ushort* __restrict__ W3_b) {
    int i = blockIdx.x * 256 + threadIdx.x;
    if (i < 128 * 256) {
        int c = i >> 8, k = i & 255;
        float v = (k < 128) ? (W2[c * 384 + k] + W2[c * 384 + 128 + k])
                            : W2[c * 384 + 128 + k];
        Wz_b[i] = f2bf(v);
    } else if (i < 128 * 256 + 128 * 128) {
        int j = i - 128 * 256;
        W1_b[j] = f2bf(W1[j]);
    } else if (i < 128 * 256 + 128 * 128 + 128 * 256) {
        int j = i - 128 * 256 - 128 * 128;
        W3_b[j] = f2bf(W3[j]);
    }
}

// ---------------- aggregate: per-dst register max+sum, bf16 in/out ----------------
// 64 lanes per dst node (4 nodes / 256-block); lane owns features 2f, 2f+1.
__global__ __launch_bounds__(256)
void aggregate(const unsigned int* __restrict__ fs_b, const int* __restrict__ esrc,
               const int* __restrict__ offs,
               unsigned int* __restrict__ mx_b, unsigned int* __restrict__ sm_b) {
    int nid = blockIdx.x * 4 + (threadIdx.x >> 6);
    int f2 = threadIdx.x & 63;                 // uint index within row (2 feats)
    if (nid >= NDST) return;
    int e0 = offs[nid];
    int e1 = offs[nid + 1];
    float mx0 = -INFINITY, mx1 = -INFINITY, s0 = 0.f, s1 = 0.f;
    int e = e0;
    for (; e + 4 <= e1; e += 4) {
        int i0 = esrc[e], i1 = esrc[e + 1], i2 = esrc[e + 2], i3 = esrc[e + 3];
        unsigned int u0 = fs_b[(size_t)i0 * 64 + f2];
        unsigned int u1 = fs_b[(size_t)i1 * 64 + f2];
        unsigned int u2 = fs_b[(size_t)i2 * 64 + f2];
        unsigned int u3 = fs_b[(size_t)i3 * 64 + f2];
        float a0 = bflo(u0), b0 = bfhi(u0);
        float a1 = bflo(u1), b1 = bfhi(u1);
        float a2 = bflo(u2), b2 = bfhi(u2);
        float a3 = bflo(u3), b3 = bfhi(u3);
        mx0 = fmaxf(fmaxf(fmaxf(mx0, a0), a1), fmaxf(a2, a3));
        mx1 = fmaxf(fmaxf(fmaxf(mx1, b0), b1), fmaxf(b2, b3));
        s0 += (a0 + a1) + (a2 + a3);
        s1 += (b0 + b1) + (b2 + b3);
    }
    for (; e < e1; ++e) {
        unsigned int u = fs_b[(size_t)esrc[e] * 64 + f2];
        float a = bflo(u), b = bfhi(u);
        mx0 = fmaxf(mx0, a);
        mx1 = fmaxf(mx1, b);
        s0 += a;
        s1 += b;
    }
    if (e0 == e1) { mx0 = 0.f; mx1 = 0.f; }    // zero-degree: -inf -> 0
    // mx values are maxima of bf16 numbers -> exactly representable; take top bits
    union { float f; unsigned int u; } c0, c1;
    c0.f = mx0; c1.f = mx1;
    mx_b[(size_t)nid * 64 + f2] = (c0.u >> 16) | (c1.u & 0xffff0000u);
    sm_b[(size_t)nid * 64 + f2] = (unsigned int)f2bf(s0) | ((unsigned int)f2bf(s1) << 16);
}

// ---------------- MFMA bf16 GEMM + bias + relu ----------------
// C[m, coloff+n] = relu(sum_k A[m,k]*W[n,k] + bias[n]), n in [0,128)
// ABF: A parts are bf16 (ushort, stride in elems) else f32 (converted on stage).
// OBF: C written as bf16 (ushort) else f32.
#define GBM 128
#define GBK 32
#define LDW 40   // padded LDS row: 80B stride -> only 2-way bank conflicts (free)

template <int ABF, int OBF>
__global__ __launch_bounds__(256)
void gemm_mfma(const void* __restrict__ a0v, int a0s,
               const void* __restrict__ a1v, int a1s,
               const ushort* __restrict__ Wb,
               const float* __restrict__ bias,
               void* __restrict__ Cv, int ldc, int coloff,
               int M, int K) {
    __shared__ ushort As[GBM * LDW];
    __shared__ ushort Ws[128 * LDW];
    int tid = threadIdx.x;
    int bm = blockIdx.x * GBM;
    int wid = tid >> 6, lane = tid & 63;
    int wm = (wid & 1) * 64, wn = (wid >> 1) * 64;
    int lrow = lane & 15, lk8 = (lane >> 4) * 8;

    f32x4 acc[4][4];
    #pragma unroll
    for (int i = 0; i < 4; ++i)
        #pragma unroll
        for (int j = 0; j < 4; ++j)
            acc[i][j] = (f32x4){0.f, 0.f, 0.f, 0.f};

    int sr = tid >> 1;            // staged row 0..127
    int skh = (tid & 1) * 16;     // k-half (16 elems)

    for (int k0 = 0; k0 < K; k0 += GBK) {
        int part = k0 >> 7;
        int kl = (k0 & 127) + skh;
        int m = bm + sr;
        uint4 w0, w1;
        if (ABF) {
            const ushort* ap = part ? (const ushort*)a1v : (const ushort*)a0v;
            int as = part ? a1s : a0s;
            if (m < M) {
                const ushort* p = ap + (size_t)m * as + kl;
                w0 = *(const uint4*)p;
                w1 = *(const uint4*)(p + 8);
            } else {
                w0 = make_uint4(0, 0, 0, 0); w1 = w0;
            }
        } else {
            const float* ap = part ? (const float*)a1v : (const float*)a0v;
            int as = part ? a1s : a0s;
            unsigned int pk[8];
            if (m < M) {
                const float* p = ap + (size_t)m * as + kl;
                #pragma unroll
                for (int j = 0; j < 8; ++j) {
                    float x = p[2 * j], y = p[2 * j + 1];
                    pk[j] = (unsigned int)f2bf(x) | ((unsigned int)f2bf(y) << 16);
                }
            } else {
                #pragma unroll
                for (int j = 0; j < 8; ++j) pk[j] = 0;
            }
            w0 = make_uint4(pk[0], pk[1], pk[2], pk[3]);
            w1 = make_uint4(pk[4], pk[5], pk[6], pk[7]);
        }
        *(uint4*)&As[sr * LDW + skh] = w0;
        *(uint4*)&As[sr * LDW + skh + 8] = w1;

        const ushort* wp = Wb + (size_t)sr * K + k0 + skh;
        uint4 v0 = *(const uint4*)wp;
        uint4 v1 = *(const uint4*)(wp + 8);
        *(uint4*)&Ws[sr * LDW + skh] = v0;
        *(uint4*)&Ws[sr * LDW + skh + 8] = v1;
        __syncthreads();

        bf16x8 af[4], bfr[4];
        #pragma unroll
        for (int mi = 0; mi < 4; ++mi)
            af[mi] = *(const bf16x8*)&As[(wm + mi * 16 + lrow) * LDW + lk8];
        #pragma unroll
        for (int ni = 0; ni < 4; ++ni)
            bfr[ni] = *(const bf16x8*)&Ws[(wn + ni * 16 + lrow) * LDW + lk8];
        #pragma unroll
        for (int mi = 0; mi < 4; ++mi)
            #pragma unroll
            for (int ni = 0; ni < 4; ++ni)
                acc[mi][ni] = __builtin_amdgcn_mfma_f32_16x16x32_bf16(
                    af[mi], bfr[ni], acc[mi][ni], 0, 0, 0);
        __syncthreads();
    }

    int rbase = (lane >> 4) * 4;
    #pragma unroll
    for (int ni = 0; ni < 4; ++ni) {
        int n = wn + ni * 16 + lrow;
        float bv = bias[n];
        #pragma unroll
        for (int mi = 0; mi < 4; ++mi) {
            #pragma unroll
            for (int r = 0; r < 4; ++r) {
                int m = bm + wm + mi * 16 + rbase + r;
                if (m < M) {
                    float v = fmaxf(acc[mi][ni][r] + bv, 0.f);
                    if (OBF) ((ushort*)Cv)[(size_t)m * ldc + coloff + n] = f2bf(v);
                    else     ((float*)Cv)[(size_t)m * ldc + coloff + n] = v;
                }
            }
        }
    }
}

extern "C" void kernel_launch(void* const* d_in, const int* in_sizes, int n_in,
                              void* d_out, int out_size, void* d_ws, size_t ws_size,
                              hipStream_t stream) {
    const float* feat_src = (const float*)d_in[0];
    const float* feat_dst = (const float*)d_in[1];
    const float* W1 = (const float*)d_in[2];
    const float* b1 = (const float*)d_in[3];
    const float* W2 = (const float*)d_in[4];
    const float* b2 = (const float*)d_in[5];
    const float* W3 = (const float*)d_in[6];
    const float* b3 = (const float*)d_in[7];
    const int* src_idx = (const int*)d_in[8];
    const int* dst_idx = (const int*)d_in[9];

    float* out = (float*)d_out;

    unsigned int* fs_b = (unsigned int*)d_ws;                 // NSRC*64 u32 (bf16x2)
    unsigned int* mx_b = fs_b + (size_t)NSRC * 64;            // NDST*64 u32
    unsigned int* sm_b = mx_b + (size_t)NDST * 64;            // NDST*64 u32
    ushort* h_b  = (ushort*)(sm_b + (size_t)NDST * 64);       // NDST*256 bf16
    ushort* Wz_b = h_b + (size_t)NDST * 256;                  // 128*256
    ushort* W1_b = Wz_b + 128 * 256;                          // 128*128
    ushort* W3_b = W1_b + 128 * 128;                          // 128*256
    int* cnt     = (int*)(W3_b + 128 * 256);                  // NDST
    int* offs    = cnt + NDST;                                // NDST+1
    int* cursor  = offs + NDST + 1;                           // NDST
    int* esrc    = cursor + NDST;                             // NEDGE
    int* bsum    = esrc + NEDGE;                              // 256
    int* bpre    = bsum + 256;                                // 256

    const int NB = (NDST + 255) / 256;   // 196

    // CSR build
    zero_cnt<<<NB, 256, 0, stream>>>(cnt);
    count_deg<<<(NEDGE + 255) / 256, 256, 0, stream>>>(dst_idx, cnt);
    scan_phase1<<<NB, 256, 0, stream>>>(cnt, bsum);
    scan_phase2<<<1, 256, 0, stream>>>(bsum, bpre, NB);
    scan_phase3<<<NB, 256, 0, stream>>>(cnt, bpre, offs, cursor);
    scatter_edges<<<(NEDGE + 255) / 256, 256, 0, stream>>>(src_idx, dst_idx, cursor, esrc);

    // conversions / weight prep
    conv_fs<<<(NSRC * DF / 4 + 255) / 256, 256, 0, stream>>>(feat_src, fs_b);
    prep_weights<<<(128 * 256 * 2 + 128 * 128 + 255) / 256, 256, 0, stream>>>(
        W2, W1, W3, Wz_b, W1_b, W3_b);

    // z1 = feat_dst @ W1^T + b1, relu -> h_b[:, 128:256]   (independent of CSR)
    dim3 ggrid((NDST + GBM - 1) / GBM, 1);
    gemm_mfma<0, 1><<<ggrid, 256, 0, stream>>>(feat_dst, DF, nullptr, 0,
                                               W1_b, b1, h_b, 256, 128, NDST, 128);

    // aggregation (bf16 gather, bf16 out)
    aggregate<<<(NDST + 3) / 4, 256, 0, stream>>>(fs_b, esrc, offs, mx_b, sm_b);

    // z2 = [mx|sm] @ Wz^T + b2, relu -> h_b[:, 0:128]
    gemm_mfma<1, 1><<<ggrid, 256, 0, stream>>>(mx_b, DF, sm_b, DF,
                                               Wz_b, b2, h_b, 256, 0, NDST, 256);
    // out = relu(h @ W3^T + b3)
    gemm_mfma<1, 0><<<ggrid, 256, 0, stream>>>(h_b, 256, h_b + 128, 256,
                                               W3_b, b3, out, DF, 0, NDST, 256);
}